// Round 10
// baseline (326.473 us; speedup 1.0000x reference)
//
#include <hip/hip_runtime.h>
#include <stdint.h>

// LinearBin: out = x @ sign(W)^T + bias   (B=131072, IN=OUT=512, fp32)
// v10: persistent blocks, engineered phase overlap. grid=256 (1 block/CU),
//      each block runs 8 strips of BM=64 rows with ping-pong 2x64KB LDS.
//      Per strip: issue next strip's global loads BEFORE the K-loop (HBM
//      streams under the L2-bound K-loop), K-loop = v8 body with 2-deep
//      B-fragment ring, then cvt+ds_write next buffer, stores drain under
//      the next K-loop. ONE barrier per strip. B L2 traffic stays 1.0GB.

#define BATCH   131072
#define IN_F    512
#define OUT_F   512
#define BM      64
#define NKT     32            // K-steps of 16
#define NS      8             // strips per block
#define GRID    256

using f32x4  = __attribute__((ext_vector_type(4))) float;
using f32x16 = __attribute__((ext_vector_type(16))) float;
using short8 = __attribute__((ext_vector_type(8))) short;
using usv8   = __attribute__((ext_vector_type(8))) unsigned short;
using u32    = uint32_t;

// ---------------- prep: binarize W into 32x32x16-fragment-major bf16 --------
// (verified r6/r8)  wf[((kt*16+nf)*64+l)*8+j] = sign(W[nf*32+(l&31)][kt*16+(l>>5)*8+j])
__global__ void prep_w(const float* __restrict__ W, unsigned short* __restrict__ wf) {
    int t = blockIdx.x * blockDim.x + threadIdx.x; // 32768 threads
    int l  = t & 63;
    int nf = (t >> 6) & 15;
    int kt = t >> 10;
    int n = nf * 32 + (l & 31);
    int k = kt * 16 + ((l >> 5) << 3);
    const float* src = W + (size_t)n * IN_F + k;
    f32x4 w0 = *(const f32x4*)(src);
    f32x4 w1 = *(const f32x4*)(src + 4);
    usv8 o;
#pragma unroll
    for (int j = 0; j < 4; ++j) {
        o[j]     = (w0[j] >= 0.0f) ? 0x3F80u : 0xBF80u; // +1.0 / -1.0 bf16
        o[j + 4] = (w1[j] >= 0.0f) ? 0x3F80u : 0xBF80u;
    }
    *(usv8*)(wf + (size_t)t * 8) = o;
}

// ---------------- GEMM: persistent, ping-pong LDS, 1 barrier/strip ----------
__global__ __launch_bounds__(512, 2) void gemm_bin(
    const float* __restrict__ X, const unsigned short* __restrict__ WF,
    const float* __restrict__ bias, float* __restrict__ out) {

    // two 64KB buffers: [buf][64 rows][512 bf16], 16B slots XOR-swizzled by row&7
    __shared__ __align__(16) char smem[2 * BM * IN_F * 2]; // 128KB

    const int tid  = threadIdx.x;
    const int lane = tid & 63;
    const int wv   = tid >> 6;                 // 0..7 -> 64-col strip
    const size_t row0 = (size_t)blockIdx.x * (NS * BM);

    // ---- staging geometry (16 f32x4 per thread = whole 64x512 fp32 strip) ----
    const int sr   = tid >> 3;                 // 0..63
    const int sg   = tid & 7;
    const int sswz = (sr & 7) << 4;
    const float* xbase = X + (row0 + sr) * IN_F + sg * 8;

    // ---- A-frag geometry (carry-free XOR, verified v8) ----
    const int arow = (lane & 31) * 1024;
    const int ak4  = (lane >> 5) << 4;
    const int aswz = (lane & 7) << 4;

    // ---- B geometry: fragment-major, nf = wv*2 + fn ----
    const short8* wb = (const short8*)WF + ((size_t)(wv * 2) * 64 + lane);

    const float bv0 = bias[wv * 64 + (lane & 31)];
    const float bv1 = bias[wv * 64 + 32 + (lane & 31)];

    f32x4  stg[16];
    f32x16 acc[2][2];

#define STG_LOAD(s_)                                                           \
    {                                                                          \
        const float* xr_ = xbase + (size_t)(s_) * (BM * IN_F);                 \
        _Pragma("unroll")                                                      \
        for (int p = 0; p < 8; ++p) {                                          \
            stg[2 * p]     = *(const f32x4*)(xr_ + p * 64);                    \
            stg[2 * p + 1] = *(const f32x4*)(xr_ + p * 64 + 4);                \
        }                                                                      \
    }

#define STG_WRITE(b_)                                                          \
    {                                                                          \
        char* lrow_ = smem + (b_) * 65536 + sr * 1024;                         \
        _Pragma("unroll")                                                      \
        for (int p = 0; p < 8; ++p) {                                          \
            u32 w0, w1, w2, w3;                                                \
            asm("v_cvt_pk_bf16_f32 %0, %1, %2" : "=v"(w0)                      \
                : "v"(stg[2*p][0]), "v"(stg[2*p][1]));                         \
            asm("v_cvt_pk_bf16_f32 %0, %1, %2" : "=v"(w1)                      \
                : "v"(stg[2*p][2]), "v"(stg[2*p][3]));                         \
            asm("v_cvt_pk_bf16_f32 %0, %1, %2" : "=v"(w2)                      \
                : "v"(stg[2*p+1][0]), "v"(stg[2*p+1][1]));                     \
            asm("v_cvt_pk_bf16_f32 %0, %1, %2" : "=v"(w3)                      \
                : "v"(stg[2*p+1][2]), "v"(stg[2*p+1][3]));                     \
            union { u32 w[4]; usv8 v; } pk_;                                   \
            pk_.w[0] = w0; pk_.w[1] = w1; pk_.w[2] = w2; pk_.w[3] = w3;        \
            *(usv8*)(lrow_ + ((sg * 16 + p * 128) ^ sswz)) = pk_.v;            \
        }                                                                      \
    }

#define ACC_INIT                                                               \
    {                                                                          \
        _Pragma("unroll")                                                      \
        for (int r_ = 0; r_ < 16; ++r_) {                                      \
            acc[0][0][r_] = bv0; acc[0][1][r_] = bv1;                          \
            acc[1][0][r_] = bv0; acc[1][1][r_] = bv1;                          \
        }                                                                      \
    }

#define LDA(dst, kt_)                                                          \
    {                                                                          \
        const int ko_ = (((kt_) * 32) + ak4) ^ aswz;                           \
        dst[0] = *(const short8*)(lptr + arow + ko_);                          \
        dst[1] = *(const short8*)(lptr + 32768 + arow + ko_);                  \
    }

#define LDB(dst, kt_)                                                          \
    {                                                                          \
        _Pragma("unroll")                                                      \
        for (int fn = 0; fn < 2; ++fn)                                         \
            dst[fn] = wb[(kt_) * 1024 + fn * 64];                              \
    }

    // ---- prologue: stage strip 0 into buffer 0 ----
    STG_LOAD(0);
    STG_WRITE(0);
    ACC_INIT;
    __syncthreads();

#pragma unroll 1
    for (int s = 0; s < NS; ++s) {
        const int cb = s & 1;
        // 1. issue next strip's HBM loads early (drain under K-loop)
        if (s + 1 < NS) STG_LOAD(s + 1);

        // 2. K-loop on buffer cb (barrier-free; B 2-deep ring, A 1-deep)
        const char* lptr = smem + cb * 65536;
        short8 af[2][2], bf[4][2];
        LDA(af[0], 0);
        LDB(bf[0], 0);
        LDB(bf[1], 1);
#pragma unroll
        for (int kt = 0; kt < NKT; ++kt) {
            if (kt + 1 < NKT) LDA(af[(kt + 1) & 1], kt + 1);
            if (kt + 2 < NKT) LDB(bf[(kt + 2) & 3], kt + 2);
#pragma unroll
            for (int rg = 0; rg < 2; ++rg)
#pragma unroll
                for (int fn = 0; fn < 2; ++fn)
                    acc[rg][fn] = __builtin_amdgcn_mfma_f32_32x32x16_bf16(
                        af[kt & 1][rg], bf[kt & 3][fn], acc[rg][fn], 0, 0, 0);
        }

        // 3. convert + write next strip into the other buffer (waits stage loads
        //    only; other waves may still be reading buffer cb — disjoint)
        if (s + 1 < NS) STG_WRITE(cb ^ 1);

        // 4. epilogue stores for strip s (drain under next K-loop)
        {
            const size_t m0 = row0 + (size_t)s * BM;
            const int c     = lane & 31;
            const int rbase = (lane >> 5) << 2;
#pragma unroll
            for (int rg = 0; rg < 2; ++rg)
#pragma unroll
                for (int fn = 0; fn < 2; ++fn)
#pragma unroll
                    for (int r_ = 0; r_ < 16; ++r_) {
                        const int row = rg * 32 + (r_ & 3) + 8 * (r_ >> 2) + rbase;
                        out[(m0 + row) * OUT_F + wv * 64 + fn * 32 + c] =
                            acc[rg][fn][r_];
                    }
        }
        ACC_INIT;
        __syncthreads();
    }
#undef STG_LOAD
#undef STG_WRITE
#undef ACC_INIT
#undef LDA
#undef LDB
}

extern "C" void kernel_launch(void* const* d_in, const int* in_sizes, int n_in,
                              void* d_out, int out_size, void* d_ws, size_t ws_size,
                              hipStream_t stream) {
    const float* X    = (const float*)d_in[0];
    const float* W    = (const float*)d_in[1];
    const float* bias = (const float*)d_in[2];
    float* o          = (float*)d_out;
    unsigned short* wf = (unsigned short*)d_ws; // 512KB fragment-major binarized W

    hipLaunchKernelGGL(prep_w, dim3(128), dim3(256), 0, stream, W, wf);
    hipLaunchKernelGGL(gemm_bin, dim3(GRID), dim3(512), 0, stream,
                       X, wf, bias, o);
}

// Round 11
// 137.795 us; speedup vs baseline: 2.3693x; 2.3693x over previous
//
#include <hip/hip_runtime.h>
#include <stdint.h>

// LinearBin: out = x @ sign(W)^T + bias   (B=131072, IN=OUT=512, fp32)
// v11: v8 (best, 138.7us) + two latency fixes, same structure:
//      - stage phase: 4-slot register ring (load pair p || cvt+write pair p-2)
//        -> ~4 HBM loads in flight instead of serial chain
//      - K-loop: B-fragment 2-slot ring loaded 2 steps ahead (LDA(kt+1),
//        MFMA(kt), LDB(kt+2)); B prologue loads hoisted before the barrier.
//      Everything else identical to v8: BM=64, 8 waves x (64x64), 64KB LDS,
//      carry-free XOR layout, fragment-major B, bias in acc, ONE barrier.

#define BATCH   131072
#define IN_F    512
#define OUT_F   512
#define BM      64
#define NKT     32            // K-steps of 16

using f32x4  = __attribute__((ext_vector_type(4))) float;
using f32x16 = __attribute__((ext_vector_type(16))) float;
using short8 = __attribute__((ext_vector_type(8))) short;
using usv8   = __attribute__((ext_vector_type(8))) unsigned short;
using u32    = uint32_t;

// ---------------- prep: binarize W into 32x32x16-fragment-major bf16 --------
// (verified r6/r8)  wf[((kt*16+nf)*64+l)*8+j] = sign(W[nf*32+(l&31)][kt*16+(l>>5)*8+j])
__global__ void prep_w(const float* __restrict__ W, unsigned short* __restrict__ wf) {
    int t = blockIdx.x * blockDim.x + threadIdx.x; // 32768 threads
    int l  = t & 63;
    int nf = (t >> 6) & 15;
    int kt = t >> 10;
    int n = nf * 32 + (l & 31);
    int k = kt * 16 + ((l >> 5) << 3);
    const float* src = W + (size_t)n * IN_F + k;
    f32x4 w0 = *(const f32x4*)(src);
    f32x4 w1 = *(const f32x4*)(src + 4);
    usv8 o;
#pragma unroll
    for (int j = 0; j < 4; ++j) {
        o[j]     = (w0[j] >= 0.0f) ? 0x3F80u : 0xBF80u; // +1.0 / -1.0 bf16
        o[j + 4] = (w1[j] >= 0.0f) ? 0x3F80u : 0xBF80u;
    }
    *(usv8*)(wf + (size_t)t * 8) = o;
}

// ---------------- GEMM: one barrier, then barrier-free K-loop ----------------
__global__ __launch_bounds__(512, 4) void gemm_bin(
    const float* __restrict__ X, const unsigned short* __restrict__ WF,
    const float* __restrict__ bias, float* __restrict__ out) {

    // 64 rows x 512 bf16, row stride 1KB, 16B slots XOR-swizzled by (row&7).
    __shared__ __align__(16) unsigned short lds[BM * IN_F]; // 64KB

    const int tid  = threadIdx.x;
    const int lane = tid & 63;
    const int wv   = tid >> 6;              // 0..7 -> 64-col strip
    const int m0   = blockIdx.x * BM;       // grid = 2048

    // ---- B geometry (independent of LDS): fragment-major, nf = wv*2+fn ----
    const short8* wb = (const short8*)(WF) + ((size_t)(wv * 2) * 64 + lane);
#define LDB(dst, kt_)                                                          \
    {                                                                          \
        _Pragma("unroll")                                                      \
        for (int fn = 0; fn < 2; ++fn)                                         \
            dst[fn] = wb[(kt_) * 1024 + fn * 64];                              \
    }

    short8 bf[2][2];
    LDB(bf[0], 0);      // issued before staging: drains with it
    LDB(bf[1], 1);

    // ---- stage whole x-strip as bf16 (once), 4-slot load ring ----
    {
        const int r  = tid >> 3;            // 0..63
        const int sg = tid & 7;
        const float* xr = X + (size_t)(m0 + r) * IN_F;
        char* lrow = (char*)lds + r * 1024;
        const int swz = (r & 7) << 4;
        f32x4 ra[4], rb[4];
#pragma unroll
        for (int p = 0; p < 10; ++p) {
            if (p < 8) {
                const int f0 = sg * 8 + p * 64;
                ra[p & 3] = *(const f32x4*)(xr + f0);
                rb[p & 3] = *(const f32x4*)(xr + f0 + 4);
            }
            if (p >= 2) {
                const int q = p - 2;
                u32 w0, w1, w2, w3;
                asm("v_cvt_pk_bf16_f32 %0, %1, %2" : "=v"(w0)
                    : "v"(ra[q & 3][0]), "v"(ra[q & 3][1]));
                asm("v_cvt_pk_bf16_f32 %0, %1, %2" : "=v"(w1)
                    : "v"(ra[q & 3][2]), "v"(ra[q & 3][3]));
                asm("v_cvt_pk_bf16_f32 %0, %1, %2" : "=v"(w2)
                    : "v"(rb[q & 3][0]), "v"(rb[q & 3][1]));
                asm("v_cvt_pk_bf16_f32 %0, %1, %2" : "=v"(w3)
                    : "v"(rb[q & 3][2]), "v"(rb[q & 3][3]));
                union { u32 w[4]; usv8 v; } pk;
                pk.w[0] = w0; pk.w[1] = w1; pk.w[2] = w2; pk.w[3] = w3;
                *(usv8*)(lrow + ((sg * 16 + q * 128) ^ swz)) = pk.v;
            }
        }
    }

    // ---- bias -> accumulator init (C/D col = lane&31; bias is col-only) ----
    f32x16 acc[2][2];
#pragma unroll
    for (int fn = 0; fn < 2; ++fn) {
        const float bv = bias[wv * 64 + fn * 32 + (lane & 31)];
#pragma unroll
        for (int rg = 0; rg < 2; ++rg)
#pragma unroll
            for (int r = 0; r < 16; ++r) acc[rg][fn][r] = bv;
    }
    __syncthreads();   // the ONLY barrier

    // ---- A geometry: row rg*32+(l&31), slot byte carry-free XOR (v8) ----
    const int arow  = (lane & 31) * 1024;
    const int ak4   = (lane >> 5) << 4;
    const int aswz  = (lane & 7) << 4;
    const char* lptr = (const char*)lds;

#define LDA(dst, kt_)                                                          \
    {                                                                          \
        const int koff_ = ((kt_) * 32 + ak4) ^ aswz;                           \
        _Pragma("unroll")                                                      \
        for (int rg = 0; rg < 2; ++rg)                                         \
            dst[rg] = *(const short8*)(lptr + rg * 32768 + arow + koff_);      \
    }

    short8 af[2][2];
    LDA(af[0], 0);

#pragma unroll
    for (int kt = 0; kt < NKT; ++kt) {
        const int cur = kt & 1;
        if (kt < NKT - 1) LDA(af[cur ^ 1], kt + 1);
#pragma unroll
        for (int rg = 0; rg < 2; ++rg)
#pragma unroll
            for (int fn = 0; fn < 2; ++fn)
                acc[rg][fn] = __builtin_amdgcn_mfma_f32_32x32x16_bf16(
                    af[cur][rg], bf[cur][fn], acc[rg][fn], 0, 0, 0);
        if (kt < NKT - 2) LDB(bf[cur], kt + 2);   // 2-ahead, post-consume slot
    }
#undef LDA
#undef LDB

    // ---- epilogue: direct stores (bias already in acc) ----
    // C/D: col = lane&31, row = (r&3) + 8*(r>>2) + 4*(lane>>5)
    const int c     = lane & 31;
    const int rbase = (lane >> 5) << 2;
#pragma unroll
    for (int rg = 0; rg < 2; ++rg)
#pragma unroll
        for (int fn = 0; fn < 2; ++fn)
#pragma unroll
            for (int r = 0; r < 16; ++r) {
                const int row = rg * 32 + (r & 3) + 8 * (r >> 2) + rbase;
                out[(size_t)(m0 + row) * OUT_F + wv * 64 + fn * 32 + c] =
                    acc[rg][fn][r];
            }
}

extern "C" void kernel_launch(void* const* d_in, const int* in_sizes, int n_in,
                              void* d_out, int out_size, void* d_ws, size_t ws_size,
                              hipStream_t stream) {
    const float* X    = (const float*)d_in[0];
    const float* W    = (const float*)d_in[1];
    const float* bias = (const float*)d_in[2];
    float* o          = (float*)d_out;
    unsigned short* wf = (unsigned short*)d_ws; // 512KB fragment-major binarized W

    hipLaunchKernelGGL(prep_w, dim3(128), dim3(256), 0, stream, W, wf);
    hipLaunchKernelGGL(gemm_bin, dim3(BATCH / BM), dim3(512), 0, stream,
                       X, wf, bias, o);
}

// Round 12
// 136.697 us; speedup vs baseline: 2.3883x; 1.0080x over previous
//
#include <hip/hip_runtime.h>
#include <stdint.h>

// LinearBin: out = x @ sign(W)^T + bias   (B=131072, IN=OUT=512, fp32)
// v12: v8 structure + zero-register DMA staging. x streamed fp32 via
//      global_load_lds into a 4x16KB LDS ring (64 rows x 64 floats per chunk,
//      source pre-swizzled, linear dest). Counted s_waitcnt vmcnt(6/4) per
//      chunk -- next chunk's DMA stays in flight across the raw s_barrier.
//      fp32->bf16 at fragment-read time (cvt_pk under MFMA). No ds_writes,
//      no stage registers. 8 waves x (64x64 tile), 64KB LDS, 2 blocks/CU.

#define BATCH   131072
#define IN_F    512
#define OUT_F   512
#define BM      64
#define NCH     8             // K-chunks of 64 floats (4 mfma k-steps each)
#define BUFB    16384         // bytes per ring buffer

using f32x4  = __attribute__((ext_vector_type(4))) float;
using f32x16 = __attribute__((ext_vector_type(16))) float;
using short8 = __attribute__((ext_vector_type(8))) short;
using usv8   = __attribute__((ext_vector_type(8))) unsigned short;
using u32    = uint32_t;

// ---------------- prep: binarize W into 32x32x16-fragment-major bf16 --------
// (verified r6/r8)  wf[((kt*16+nf)*64+l)*8+j] = sign(W[nf*32+(l&31)][kt*16+(l>>5)*8+j])
__global__ void prep_w(const float* __restrict__ W, unsigned short* __restrict__ wf) {
    int t = blockIdx.x * blockDim.x + threadIdx.x; // 32768 threads
    int l  = t & 63;
    int nf = (t >> 6) & 15;
    int kt = t >> 10;
    int n = nf * 32 + (l & 31);
    int k = kt * 16 + ((l >> 5) << 3);
    const float* src = W + (size_t)n * IN_F + k;
    f32x4 w0 = *(const f32x4*)(src);
    f32x4 w1 = *(const f32x4*)(src + 4);
    usv8 o;
#pragma unroll
    for (int j = 0; j < 4; ++j) {
        o[j]     = (w0[j] >= 0.0f) ? 0x3F80u : 0xBF80u; // +1.0 / -1.0 bf16
        o[j + 4] = (w1[j] >= 0.0f) ? 0x3F80u : 0xBF80u;
    }
    *(usv8*)(wf + (size_t)t * 8) = o;
}

__device__ __forceinline__ void wait_vm6() { asm volatile("s_waitcnt vmcnt(6)" ::: "memory"); }
__device__ __forceinline__ void wait_vm4() { asm volatile("s_waitcnt vmcnt(4)" ::: "memory"); }

// ---------------- GEMM ----------------
__global__ __launch_bounds__(512, 4) void gemm_bin(
    const float* __restrict__ X, const unsigned short* __restrict__ WF,
    const float* __restrict__ bias, float* __restrict__ out) {

    // ring of 4 fp32 chunks: [64 rows][256B], content XOR-swizzled by (row&7)<<4
    __shared__ __align__(16) char smem[4 * BUFB];   // 64KB

    const int tid  = threadIdx.x;
    const int lane = tid & 63;
    const int wv   = tid >> 6;              // 0..7 -> 64-col strip
    const int m0   = blockIdx.x * BM;       // grid = 2048

    // ---- DMA source geometry (2 x 16B per thread per chunk) ----
    // linear LDS off o = (i*8192 + wv*1024) + lane*16 -> row = o>>8, c = o&255
    // content[r][c] = x[m0+r][ck*64 + ((c ^ ((r&7)<<4))>>2) ..+3]
    const int dr   = wv * 4 + (lane >> 4);          // i=0 row (0..31)
    const int dc   = (lane & 15) * 16;              // byte-in-row
    const int dswz = (dr & 7) << 4;                 // row+32 keeps (r&7)
    const float* src0 = X + (size_t)(m0 + dr) * IN_F + ((dc ^ dswz) >> 2);
    const float* src1 = src0 + (size_t)32 * IN_F;

#define ISSUE_DMA(ck_)                                                         \
    {                                                                          \
        char* b_ = smem + ((ck_) & 3) * BUFB + wv * 1024;                      \
        __builtin_amdgcn_global_load_lds(                                      \
            (const __attribute__((address_space(1))) void*)(src0 + (ck_) * 64),\
            (__attribute__((address_space(3))) void*)(b_), 16, 0, 0);          \
        __builtin_amdgcn_global_load_lds(                                      \
            (const __attribute__((address_space(1))) void*)(src1 + (ck_) * 64),\
            (__attribute__((address_space(3))) void*)(b_ + 8192), 16, 0, 0);   \
    }

    // ---- B geometry: fragment-major, nf = wv*2+fn (verified r6/r8) ----
    const short8* wb = (const short8*)(WF) + ((size_t)(wv * 2) * 64 + lane);
#define LDB(dst, g_)                                                           \
    {                                                                          \
        _Pragma("unroll")                                                      \
        for (int fn = 0; fn < 2; ++fn)                                         \
            dst[fn] = wb[(g_) * 1024 + fn * 64];                               \
    }

    // ---- A-frag geometry: lane l -> row rg*32+(l&31), floats kt4*16+(l>>5)*8
    const int arow = (lane & 31) * 256;
    const int aq32 = (lane >> 5) << 5;
    const int aswz = (lane & 7) << 4;

#define LDA_CVT(dst, ab_, kt4_)                                                \
    {                                                                          \
        _Pragma("unroll")                                                      \
        for (int rg = 0; rg < 2; ++rg) {                                       \
            const char* p_  = (ab_) + rg * 8192 + arow;                        \
            const int  blo_ = (((kt4_) << 6) + aq32) ^ aswz;                   \
            f32x4 lo_ = *(const f32x4*)(p_ + blo_);                            \
            f32x4 hi_ = *(const f32x4*)(p_ + (blo_ ^ 16));                     \
            u32 w0_, w1_, w2_, w3_;                                            \
            asm("v_cvt_pk_bf16_f32 %0, %1, %2" : "=v"(w0_)                     \
                : "v"(lo_[0]), "v"(lo_[1]));                                   \
            asm("v_cvt_pk_bf16_f32 %0, %1, %2" : "=v"(w1_)                     \
                : "v"(lo_[2]), "v"(lo_[3]));                                   \
            asm("v_cvt_pk_bf16_f32 %0, %1, %2" : "=v"(w2_)                     \
                : "v"(hi_[0]), "v"(hi_[1]));                                   \
            asm("v_cvt_pk_bf16_f32 %0, %1, %2" : "=v"(w3_)                     \
                : "v"(hi_[2]), "v"(hi_[3]));                                   \
            union { u32 w[4]; short8 v; } pk_;                                 \
            pk_.w[0] = w0_; pk_.w[1] = w1_; pk_.w[2] = w2_; pk_.w[3] = w3_;    \
            dst[rg] = pk_.v;                                                   \
        }                                                                      \
    }

    // ---- bias -> accumulator init ----
    f32x16 acc[2][2];
#pragma unroll
    for (int fn = 0; fn < 2; ++fn) {
        const float bv = bias[wv * 64 + fn * 32 + (lane & 31)];
#pragma unroll
        for (int rg = 0; rg < 2; ++rg)
#pragma unroll
            for (int r = 0; r < 16; ++r) acc[rg][fn][r] = bv;
    }

    // ---- prologue: two chunks of DMA in flight ----
    ISSUE_DMA(0);
    ISSUE_DMA(1);

    short8 bf[2][2];
#pragma unroll
    for (int ck = 0; ck < NCH; ++ck) {
        // chunk-B prologue (4 counted VMEM loads, before the wait)
        LDB(bf[0], ck * 4 + 0);
        LDB(bf[1], ck * 4 + 1);
        __builtin_amdgcn_sched_barrier(0);
        // exact count: DMA(ck):2 [+ DMA(ck+1):2 if ck<7] + B:4 outstanding
        if (ck < NCH - 1) wait_vm6(); else wait_vm4();
        __builtin_amdgcn_sched_barrier(0);
        __builtin_amdgcn_s_barrier();
        __builtin_amdgcn_sched_barrier(0);
        if (ck + 2 < NCH) ISSUE_DMA(ck + 2);   // overwrites buf of ck-2 (safe)

        const char* ab = smem + (ck & 3) * BUFB;
        short8 af[2];
#pragma unroll
        for (int kt4 = 0; kt4 < 4; ++kt4) {
            LDA_CVT(af, ab, kt4);
#pragma unroll
            for (int rg = 0; rg < 2; ++rg)
#pragma unroll
                for (int fn = 0; fn < 2; ++fn)
                    acc[rg][fn] = __builtin_amdgcn_mfma_f32_32x32x16_bf16(
                        af[rg], bf[kt4 & 1][fn], acc[rg][fn], 0, 0, 0);
            if (kt4 < 2) LDB(bf[kt4 & 1], ck * 4 + kt4 + 2);
        }
    }
#undef ISSUE_DMA
#undef LDB
#undef LDA_CVT

    // ---- epilogue: direct stores (bias already in acc) ----
    // C/D: col = lane&31, row = (r&3) + 8*(r>>2) + 4*(lane>>5)
    const int c     = lane & 31;
    const int rbase = (lane >> 5) << 2;
#pragma unroll
    for (int rg = 0; rg < 2; ++rg)
#pragma unroll
        for (int fn = 0; fn < 2; ++fn)
#pragma unroll
            for (int r = 0; r < 16; ++r) {
                const int row = rg * 32 + (r & 3) + 8 * (r >> 2) + rbase;
                out[(size_t)(m0 + row) * OUT_F + wv * 64 + fn * 32 + c] =
                    acc[rg][fn][r];
            }
}

extern "C" void kernel_launch(void* const* d_in, const int* in_sizes, int n_in,
                              void* d_out, int out_size, void* d_ws, size_t ws_size,
                              hipStream_t stream) {
    const float* X    = (const float*)d_in[0];
    const float* W    = (const float*)d_in[1];
    const float* bias = (const float*)d_in[2];
    float* o          = (float*)d_out;
    unsigned short* wf = (unsigned short*)d_ws; // 512KB fragment-major binarized W

    hipLaunchKernelGGL(prep_w, dim3(128), dim3(256), 0, stream, W, wf);
    hipLaunchKernelGGL(gemm_bin, dim3(BATCH / BM), dim3(512), 0, stream,
                       X, wf, bias, o);
}